// Round 1
// baseline (2042.784 us; speedup 1.0000x reference)
//
#include <hip/hip_runtime.h>
#include <math.h>

// ---------------- workspace layout (bytes) ----------------
constexpr size_t XW_OFF  = 0;                                   // 65536*384 f32 = 96 MB
constexpr size_t O1_OFF  = XW_OFF + 65536ull * 384 * 4;         // 32 MB
constexpr size_t O2_OFF  = O1_OFF + 512ull * 128 * 128 * 4;     // 32 MB
constexpr size_t Y0_OFF  = O2_OFF + 512ull * 128 * 128 * 4;     // 128 KB
constexpr size_t Y1_OFF  = Y0_OFF + 256ull * 128 * 4;           // 128 KB
constexpr size_t MMD_OFF = Y1_OFF + 256ull * 128 * 4;           // 1 KB
constexpr size_t WTS_OFF = MMD_OFF + 256 * 4;                   // 1 KB
constexpr size_t BW_OFF  = WTS_OFF + 256 * 4;                   // 1 KB

// ---------------- K1/K3: C[M][N] = A[M][K] @ W[N][K]^T + bias[N] ----------------
// M=65536, N=384, K=128. 64x64 tile, K chunks of 32, 4x4 microtile (rows ty+16i).
__global__ __launch_bounds__(256) void gemm64(const float* __restrict__ A,
                                              const float* __restrict__ W,
                                              const float* __restrict__ bias,
                                              float* __restrict__ C,
                                              int M, int N, int K)
{
    __shared__ __align__(16) float As[64][36];
    __shared__ __align__(16) float Ws[64][36];
    const int tid = threadIdx.x;
    const int tx = tid & 15, ty = tid >> 4;
    const int m0 = blockIdx.x * 64, n0 = blockIdx.y * 64;

    float acc[4][4];
#pragma unroll
    for (int i = 0; i < 4; ++i)
#pragma unroll
        for (int j = 0; j < 4; ++j) acc[i][j] = 0.f;

    for (int kc = 0; kc < K; kc += 32) {
#pragma unroll
        for (int it = 0; it < 2; ++it) {
            int idx = tid + it * 256;          // 0..511
            int row = idx >> 3;
            int c4  = (idx & 7) * 4;
            float4 va = *(const float4*)(A + (size_t)(m0 + row) * K + kc + c4);
            *(float4*)&As[row][c4] = va;
            float4 vw = *(const float4*)(W + (size_t)(n0 + row) * K + kc + c4);
            *(float4*)&Ws[row][c4] = vw;
        }
        __syncthreads();
#pragma unroll
        for (int k0 = 0; k0 < 32; k0 += 4) {
            float4 a4[4], w4[4];
#pragma unroll
            for (int i = 0; i < 4; ++i) a4[i] = *(float4*)&As[ty + 16 * i][k0];
#pragma unroll
            for (int j = 0; j < 4; ++j) w4[j] = *(float4*)&Ws[tx + 16 * j][k0];
#pragma unroll
            for (int i = 0; i < 4; ++i)
#pragma unroll
                for (int j = 0; j < 4; ++j) {
                    acc[i][j] += a4[i].x * w4[j].x + a4[i].y * w4[j].y +
                                 a4[i].z * w4[j].z + a4[i].w * w4[j].w;
                }
        }
        __syncthreads();
    }
#pragma unroll
    for (int i = 0; i < 4; ++i)
#pragma unroll
        for (int j = 0; j < 4; ++j) {
            int r = m0 + ty + 16 * i, c = n0 + tx + 16 * j;
            C[(size_t)r * N + c] = acc[i][j] + bias[c];
        }
}

// ---------------- K2/K4: GRU scan, one block per batch row ----------------
// xw[b][t][j] (j in [0,384)), whh[384][128], bhh[384]; out[b][t][u] u in [0,128)
__global__ __launch_bounds__(384, 3) void gru_scan(const float* __restrict__ xw,
                                                   const float* __restrict__ whh,
                                                   const float* __restrict__ bhh,
                                                   float* __restrict__ out)
{
    const int b = blockIdx.x;
    const int j = threadIdx.x;
    float w[128];
    const float* wr = whh + (size_t)j * 128;
#pragma unroll
    for (int k = 0; k < 128; k += 4) {
        float4 t = *(const float4*)(wr + k);
        w[k] = t.x; w[k + 1] = t.y; w[k + 2] = t.z; w[k + 3] = t.w;
    }
    const float bj = bhh[j];
    __shared__ __align__(16) float h_s[128];
    __shared__ float rz_s[256];
    __shared__ float xn_s[128];
    __shared__ float hn_s[128];
    if (j < 128) h_s[j] = 0.f;
    __syncthreads();

    const float* xwb = xw + (size_t)b * 128 * 384;
    const int g = j >> 7, u = j & 127;

    for (int t = 0; t < 128; ++t) {
        float xv = xwb[t * 384 + j];
        float acc = bj;
#pragma unroll
        for (int k = 0; k < 128; k += 4) {
            float4 hv = *(float4*)&h_s[k];
            acc += w[k] * hv.x + w[k + 1] * hv.y + w[k + 2] * hv.z + w[k + 3] * hv.w;
        }
        if (g == 0)      rz_s[u] = xv + acc;
        else if (g == 1) rz_s[128 + u] = xv + acc;
        else             { xn_s[u] = xv; hn_s[u] = acc; }
        __syncthreads();
        if (j < 128) {
            float r = 1.f / (1.f + __expf(-rz_s[j]));
            float z = 1.f / (1.f + __expf(-rz_s[128 + j]));
            float xa = xn_s[j] + r * hn_s[j];
            float e = __expf(-2.f * fabsf(xa));
            float th = (1.f - e) / (1.f + e);
            th = copysignf(th, xa);
            float hnew = (1.f - z) * th + z * h_s[j];
            h_s[j] = hnew;
            out[((size_t)b * 128 + t) * 128 + j] = hnew;
        }
        __syncthreads();
    }
}

// ---------------- K5: y[256][128] += xall @ gw^T (split-K, atomic) ----------------
// xall[b][kappa]: s=kappa>>8, half=(kappa>>7)&1, h=kappa&127 -> o[((b+256*half)*128+s)*128+h]
__global__ __launch_bounds__(256) void gate_gemm(const float* __restrict__ o,
                                                 const float* __restrict__ gw,
                                                 float* __restrict__ y)
{
    __shared__ __align__(16) float As[64][36];
    __shared__ __align__(16) float Ws[64][36];
    const int tid = threadIdx.x;
    const int tx = tid & 15, ty = tid >> 4;
    const int m0 = blockIdx.x * 64, n0 = blockIdx.y * 64;
    const int k0beg = blockIdx.z * 1024;

    float acc[4][4];
#pragma unroll
    for (int i = 0; i < 4; ++i)
#pragma unroll
        for (int j = 0; j < 4; ++j) acc[i][j] = 0.f;

    for (int kc = k0beg; kc < k0beg + 1024; kc += 32) {
#pragma unroll
        for (int it = 0; it < 2; ++it) {
            int idx = tid + it * 256;
            int row = idx >> 3;
            int c4  = (idx & 7) * 4;
            int kap = kc + c4;
            int s = kap >> 8, half = (kap >> 7) & 1, h = kap & 127;
            float4 va = *(const float4*)(o + ((size_t)(m0 + row + 256 * half) * 128 + s) * 128 + h);
            *(float4*)&As[row][c4] = va;
            float4 vw = *(const float4*)(gw + (size_t)(n0 + row) * 32768 + kap);
            *(float4*)&Ws[row][c4] = vw;
        }
        __syncthreads();
#pragma unroll
        for (int k0 = 0; k0 < 32; k0 += 4) {
            float4 a4[4], w4[4];
#pragma unroll
            for (int i = 0; i < 4; ++i) a4[i] = *(float4*)&As[ty + 16 * i][k0];
#pragma unroll
            for (int j = 0; j < 4; ++j) w4[j] = *(float4*)&Ws[tx + 16 * j][k0];
#pragma unroll
            for (int i = 0; i < 4; ++i)
#pragma unroll
                for (int j = 0; j < 4; ++j) {
                    acc[i][j] += a4[i].x * w4[j].x + a4[i].y * w4[j].y +
                                 a4[i].z * w4[j].z + a4[i].w * w4[j].w;
                }
        }
        __syncthreads();
    }
#pragma unroll
    for (int i = 0; i < 4; ++i)
#pragma unroll
        for (int j = 0; j < 4; ++j) {
            int r = m0 + ty + 16 * i, c = n0 + tx + 16 * j;
            atomicAdd(&y[r * 128 + c], acc[i][j]);
        }
}

// ---------------- K6: BN + sigmoid-mean + softmax -> weights (128) ----------------
__global__ void gate_reduce(const float* __restrict__ y,
                            const float* __restrict__ gamma,
                            const float* __restrict__ beta,
                            float* __restrict__ wts_ws,
                            float* __restrict__ wts_out)
{
    const int o = threadIdx.x;   // 128 threads
    float sum = 0.f, sumsq = 0.f;
    for (int b = 0; b < 256; ++b) {
        float v = y[b * 128 + o];
        sum += v; sumsq += v * v;
    }
    float m = sum * (1.f / 256.f);
    float var = sumsq * (1.f / 256.f) - m * m;
    float inv = rsqrtf(var + 1e-5f);
    float g = gamma[o], be = beta[o];
    float sw = 0.f;
    for (int b = 0; b < 256; ++b) {
        float v = y[b * 128 + o];
        float t = g * (v - m) * inv + be;
        sw += 1.f / (1.f + __expf(-t));
    }
    float wo = sw * (1.f / 256.f);

    __shared__ float red[128];
    red[o] = wo;
    __syncthreads();
    for (int st = 64; st > 0; st >>= 1) {
        if (o < st) red[o] = fmaxf(red[o], red[o + st]);
        __syncthreads();
    }
    float mx = red[0];
    __syncthreads();
    float e = __expf(wo - mx);
    red[o] = e;
    __syncthreads();
    for (int st = 64; st > 0; st >>= 1) {
        if (o < st) red[o] += red[o + st];
        __syncthreads();
    }
    float r = e / red[0];
    wts_ws[o] = r;
    wts_out[o] = r;
}

// ---------------- K7: fc_out = o2[:, -1, :] @ fc_w^T + fc_b ----------------
__global__ void fc_kern(const float* __restrict__ o2,
                        const float* __restrict__ fw,
                        const float* __restrict__ fb,
                        float* __restrict__ out)
{
    int gid = blockIdx.x * blockDim.x + threadIdx.x;
    if (gid >= 3072) return;
    int b = gid / 6, oo = gid - b * 6;
    const float* xr = o2 + ((size_t)b * 128 + 127) * 128;
    const float* wr = fw + oo * 128;
    float acc = fb[oo];
#pragma unroll 16
    for (int k = 0; k < 128; ++k) acc += xr[k] * wr[k];
    out[gid] = acc;
}

// ---------------- K8: per-pair bandwidth: bw = (1024*S1 - 2*S2)/(512^2-512)/4 ----------------
__global__ void pair_stats(const float* __restrict__ o1,
                           const float* __restrict__ o2,
                           float* __restrict__ bw)
{
    const int p = blockIdx.x;          // 256 pairs
    const int l = p >> 7, s = p & 127;
    const float* o = l ? o2 : o1;
    const int tid = threadIdx.x;       // 256
    const int h = tid & 127, half = tid >> 7;

    float acc_u = 0.f, acc_sq = 0.f;
    for (int r = 0; r < 256; ++r) {
        int i = half * 256 + r;
        float v = o[((size_t)i * 128 + s) * 128 + h];
        acc_u += v; acc_sq += v * v;
    }
    __shared__ float u2[256];
    __shared__ float red[256];
    u2[tid] = acc_u;
    red[tid] = acc_sq;
    __syncthreads();
    for (int st = 128; st > 0; st >>= 1) {
        if (tid < st) red[tid] += red[tid + st];
        __syncthreads();
    }
    float S1 = red[0];
    __syncthreads();
    float uu = 0.f;
    if (tid < 128) { float t = u2[tid] + u2[tid + 128]; uu = t * t; }
    red[tid] = uu;
    __syncthreads();
    for (int st = 128; st > 0; st >>= 1) {
        if (tid < st) red[tid] += red[tid + st];
        __syncthreads();
    }
    if (tid == 0) {
        float S2 = red[0];
        float d2s = 1024.f * S1 - 2.f * S2;
        bw[p] = d2s / (512.f * 512.f - 512.f) * 0.25f;
    }
}

// ---------------- K9: MMD Gram + 5-kernel sum, symmetric tiles ----------------
__global__ __launch_bounds__(256) void mmd_kern(const float* __restrict__ o1,
                                                const float* __restrict__ o2,
                                                const float* __restrict__ bw,
                                                float* __restrict__ mmdv)
{
    // tile-pair map over (ti<=tj), 4x4 tiles of 128
    int tp = blockIdx.x;
    int ti, tj;
    if (tp < 4)      { ti = 0; tj = tp; }
    else if (tp < 7) { ti = 1; tj = tp - 3; }
    else if (tp < 9) { ti = 2; tj = tp - 5; }
    else             { ti = 3; tj = 3; }
    const int p = blockIdx.y;
    const int l = p >> 7, s = p & 127;
    const float* o = l ? o2 : o1;
    const float sgn  = ((ti < 2) == (tj < 2)) ? 1.f : -1.f;
    const float coef = sgn * ((ti == tj) ? 1.f : 2.f);

    __shared__ __align__(16) float As[128][36];
    __shared__ __align__(16) float Bs[128][36];
    __shared__ float sqA[128];
    __shared__ float sqB[128];
    __shared__ float rbuf[4];

    const int tid = threadIdx.x;
    const int tx = tid & 15, ty = tid >> 4;

    float acc[8][8];
#pragma unroll
    for (int i = 0; i < 8; ++i)
#pragma unroll
        for (int j = 0; j < 8; ++j) acc[i][j] = 0.f;
    float sqa = 0.f, sqb = 0.f;

    for (int kc = 0; kc < 128; kc += 32) {
#pragma unroll
        for (int it = 0; it < 4; ++it) {
            int idx = tid + it * 256;           // 0..1023
            int row = idx >> 3;
            int c4  = (idx & 7) * 4;
            float4 va = *(const float4*)(o + ((size_t)(ti * 128 + row) * 128 + s) * 128 + kc + c4);
            *(float4*)&As[row][c4] = va;
            float4 vb = *(const float4*)(o + ((size_t)(tj * 128 + row) * 128 + s) * 128 + kc + c4);
            *(float4*)&Bs[row][c4] = vb;
        }
        __syncthreads();
        if (tid < 128) {
#pragma unroll
            for (int k = 0; k < 32; ++k) {
                float va = As[tid][k]; sqa += va * va;
                float vb = Bs[tid][k]; sqb += vb * vb;
            }
        }
#pragma unroll
        for (int k0 = 0; k0 < 32; k0 += 4) {
            float4 a4[8], b4[8];
#pragma unroll
            for (int i = 0; i < 8; ++i) a4[i] = *(float4*)&As[ty + 16 * i][k0];
#pragma unroll
            for (int j = 0; j < 8; ++j) b4[j] = *(float4*)&Bs[tx + 16 * j][k0];
#pragma unroll
            for (int i = 0; i < 8; ++i)
#pragma unroll
                for (int j = 0; j < 8; ++j) {
                    acc[i][j] += a4[i].x * b4[j].x + a4[i].y * b4[j].y +
                                 a4[i].z * b4[j].z + a4[i].w * b4[j].w;
                }
        }
        __syncthreads();
    }
    if (tid < 128) { sqA[tid] = sqa; sqB[tid] = sqb; }
    __syncthreads();

    const float bwv = bw[p];
    float c0 = -1.f / bwv;
    float c1 = c0 * 0.5f, c2 = c1 * 0.5f, c3 = c2 * 0.5f, c4v = c3 * 0.5f;
    float tot = 0.f;
#pragma unroll
    for (int i = 0; i < 8; ++i) {
        float sa = sqA[ty + 16 * i];
#pragma unroll
        for (int j = 0; j < 8; ++j) {
            float d2 = sa + sqB[tx + 16 * j] - 2.f * acc[i][j];
            float kv = __expf(c0 * d2) + __expf(c1 * d2) + __expf(c2 * d2) +
                       __expf(c3 * d2) + __expf(c4v * d2);
            tot += kv;
        }
    }
    tot *= coef;

    // block reduce (4 waves)
    for (int off = 32; off > 0; off >>= 1) tot += __shfl_down(tot, off);
    if ((tid & 63) == 0) rbuf[tid >> 6] = tot;
    __syncthreads();
    if (tid == 0) atomicAdd(&mmdv[p], rbuf[0] + rbuf[1] + rbuf[2] + rbuf[3]);
}

// ---------------- K10: loss = sum(wts * mmd) / 65536 ----------------
__global__ void final_loss(const float* __restrict__ wts,
                           const float* __restrict__ mmdv,
                           float* __restrict__ out)
{
    const int t = threadIdx.x;  // 256
    float v = wts[t] * mmdv[t];
    __shared__ float red[256];
    red[t] = v;
    __syncthreads();
    for (int st = 128; st > 0; st >>= 1) {
        if (t < st) red[t] += red[t + st];
        __syncthreads();
    }
    if (t == 0) out[0] = red[0] * (1.f / 65536.f);
}

// ---------------- launch ----------------
extern "C" void kernel_launch(void* const* d_in, const int* in_sizes, int n_in,
                              void* d_out, int out_size, void* d_ws, size_t ws_size,
                              hipStream_t stream)
{
    (void)in_sizes; (void)n_in; (void)out_size; (void)ws_size;
    const float* x    = (const float*)d_in[0];
    const float* wih0 = (const float*)d_in[1];
    const float* whh0 = (const float*)d_in[2];
    const float* bih0 = (const float*)d_in[3];
    const float* bhh0 = (const float*)d_in[4];
    const float* wih1 = (const float*)d_in[5];
    const float* whh1 = (const float*)d_in[6];
    const float* bih1 = (const float*)d_in[7];
    const float* bhh1 = (const float*)d_in[8];
    const float* gw0  = (const float*)d_in[9];
    const float* bg0  = (const float*)d_in[11];
    const float* bb0  = (const float*)d_in[12];
    const float* gw1  = (const float*)d_in[13];
    const float* bg1  = (const float*)d_in[15];
    const float* bb1  = (const float*)d_in[16];
    const float* fcw  = (const float*)d_in[17];
    const float* fcb  = (const float*)d_in[18];

    float* out = (float*)d_out;
    char*  ws  = (char*)d_ws;
    float* xw   = (float*)(ws + XW_OFF);
    float* o1   = (float*)(ws + O1_OFF);
    float* o2   = (float*)(ws + O2_OFF);
    float* y0   = (float*)(ws + Y0_OFF);
    float* y1   = (float*)(ws + Y1_OFF);
    float* mmdv = (float*)(ws + MMD_OFF);
    float* wts  = (float*)(ws + WTS_OFF);
    float* bwv  = (float*)(ws + BW_OFF);

    // zero y0, y1, mmd (contiguous)
    hipMemsetAsync(y0, 0, (256 * 128 * 2 + 256) * sizeof(float), stream);

    gemm64<<<dim3(1024, 6), 256, 0, stream>>>(x, wih0, bih0, xw, 65536, 384, 128);
    gru_scan<<<512, 384, 0, stream>>>(xw, whh0, bhh0, o1);
    gemm64<<<dim3(1024, 6), 256, 0, stream>>>(o1, wih1, bih1, xw, 65536, 384, 128);
    gru_scan<<<512, 384, 0, stream>>>(xw, whh1, bhh1, o2);

    gate_gemm<<<dim3(4, 2, 32), 256, 0, stream>>>(o1, gw0, y0);
    gate_gemm<<<dim3(4, 2, 32), 256, 0, stream>>>(o2, gw1, y1);
    gate_reduce<<<1, 128, 0, stream>>>(y0, bg0, bb0, wts, out + 3073);
    gate_reduce<<<1, 128, 0, stream>>>(y1, bg1, bb1, wts + 128, out + 3073 + 128);

    fc_kern<<<12, 256, 0, stream>>>(o2, fcw, fcb, out);

    pair_stats<<<256, 256, 0, stream>>>(o1, o2, bwv);
    mmd_kern<<<dim3(10, 256), 256, 0, stream>>>(o1, o2, bwv, mmdv);
    final_loss<<<1, 256, 0, stream>>>(wts, mmdv, out + 3072);
}

// Round 2
// 1276.973 us; speedup vs baseline: 1.5997x; 1.5997x over previous
//
#include <hip/hip_runtime.h>
#include <math.h>

// ---------------- workspace layout (bytes) ----------------
constexpr size_t XW_OFF  = 0;                                   // 65536*384 f32 = 96 MB
constexpr size_t O1_OFF  = XW_OFF + 65536ull * 384 * 4;         // 32 MB
constexpr size_t O2_OFF  = O1_OFF + 512ull * 128 * 128 * 4;     // 32 MB
constexpr size_t Y0_OFF  = O2_OFF + 512ull * 128 * 128 * 4;     // 128 KB
constexpr size_t Y1_OFF  = Y0_OFF + 256ull * 128 * 4;           // 128 KB
constexpr size_t MMD_OFF = Y1_OFF + 256ull * 128 * 4;           // 1 KB
constexpr size_t WTS_OFF = MMD_OFF + 256 * 4;                   // 1 KB
constexpr size_t BW_OFF  = WTS_OFF + 256 * 4;                   // 1 KB

// ---------------- K1/K3: C[M][N] = A[M][K] @ W[N][K]^T + bias[N] ----------------
// M=65536, N=384, K=128. 64x64 tile, K chunks of 32, 4x4 microtile (rows ty+16i).
__global__ __launch_bounds__(256) void gemm64(const float* __restrict__ A,
                                              const float* __restrict__ W,
                                              const float* __restrict__ bias,
                                              float* __restrict__ C,
                                              int M, int N, int K)
{
    __shared__ __align__(16) float As[64][36];
    __shared__ __align__(16) float Ws[64][36];
    const int tid = threadIdx.x;
    const int tx = tid & 15, ty = tid >> 4;
    const int m0 = blockIdx.x * 64, n0 = blockIdx.y * 64;

    float acc[4][4];
#pragma unroll
    for (int i = 0; i < 4; ++i)
#pragma unroll
        for (int j = 0; j < 4; ++j) acc[i][j] = 0.f;

#pragma unroll 1
    for (int kc = 0; kc < K; kc += 32) {
#pragma unroll
        for (int it = 0; it < 2; ++it) {
            int idx = tid + it * 256;          // 0..511
            int row = idx >> 3;
            int c4  = (idx & 7) * 4;
            float4 va = *(const float4*)(A + (size_t)(m0 + row) * K + kc + c4);
            *(float4*)&As[row][c4] = va;
            float4 vw = *(const float4*)(W + (size_t)(n0 + row) * K + kc + c4);
            *(float4*)&Ws[row][c4] = vw;
        }
        __syncthreads();
#pragma unroll 1
        for (int k0 = 0; k0 < 32; k0 += 4) {
            float4 a4[4], w4[4];
#pragma unroll
            for (int i = 0; i < 4; ++i) a4[i] = *(float4*)&As[ty + 16 * i][k0];
#pragma unroll
            for (int j = 0; j < 4; ++j) w4[j] = *(float4*)&Ws[tx + 16 * j][k0];
#pragma unroll
            for (int i = 0; i < 4; ++i)
#pragma unroll
                for (int j = 0; j < 4; ++j) {
                    acc[i][j] += a4[i].x * w4[j].x + a4[i].y * w4[j].y +
                                 a4[i].z * w4[j].z + a4[i].w * w4[j].w;
                }
        }
        __syncthreads();
    }
#pragma unroll
    for (int i = 0; i < 4; ++i)
#pragma unroll
        for (int j = 0; j < 4; ++j) {
            int r = m0 + ty + 16 * i, c = n0 + tx + 16 * j;
            C[(size_t)r * N + c] = acc[i][j] + bias[c];
        }
}

// ---------------- K2/K4: GRU scan, one block per batch row ----------------
__global__ __launch_bounds__(384, 3) void gru_scan(const float* __restrict__ xw,
                                                   const float* __restrict__ whh,
                                                   const float* __restrict__ bhh,
                                                   float* __restrict__ out)
{
    const int b = blockIdx.x;
    const int j = threadIdx.x;
    float w[128];
    const float* wr = whh + (size_t)j * 128;
#pragma unroll
    for (int k = 0; k < 128; k += 4) {
        float4 t = *(const float4*)(wr + k);
        w[k] = t.x; w[k + 1] = t.y; w[k + 2] = t.z; w[k + 3] = t.w;
    }
    const float bj = bhh[j];
    __shared__ __align__(16) float h_s[128];
    __shared__ float rz_s[256];
    __shared__ float xn_s[128];
    __shared__ float hn_s[128];
    if (j < 128) h_s[j] = 0.f;
    __syncthreads();

    const float* xwb = xw + (size_t)b * 128 * 384;
    const int g = j >> 7, u = j & 127;

#pragma unroll 1
    for (int t = 0; t < 128; ++t) {
        float xv = xwb[t * 384 + j];
        float acc = bj;
#pragma unroll
        for (int k = 0; k < 128; k += 4) {
            float4 hv = *(float4*)&h_s[k];
            acc += w[k] * hv.x + w[k + 1] * hv.y + w[k + 2] * hv.z + w[k + 3] * hv.w;
        }
        if (g == 0)      rz_s[u] = xv + acc;
        else if (g == 1) rz_s[128 + u] = xv + acc;
        else             { xn_s[u] = xv; hn_s[u] = acc; }
        __syncthreads();
        if (j < 128) {
            float r = 1.f / (1.f + __expf(-rz_s[j]));
            float z = 1.f / (1.f + __expf(-rz_s[128 + j]));
            float xa = xn_s[j] + r * hn_s[j];
            float e = __expf(-2.f * fabsf(xa));
            float th = (1.f - e) / (1.f + e);
            th = copysignf(th, xa);
            float hnew = (1.f - z) * th + z * h_s[j];
            h_s[j] = hnew;
            out[((size_t)b * 128 + t) * 128 + j] = hnew;
        }
        __syncthreads();
    }
}

// ---------------- K5: y[256][128] += xall @ gw^T (split-K, atomic) ----------------
__global__ __launch_bounds__(256) void gate_gemm(const float* __restrict__ o,
                                                 const float* __restrict__ gw,
                                                 float* __restrict__ y)
{
    __shared__ __align__(16) float As[64][36];
    __shared__ __align__(16) float Ws[64][36];
    const int tid = threadIdx.x;
    const int tx = tid & 15, ty = tid >> 4;
    const int m0 = blockIdx.x * 64, n0 = blockIdx.y * 64;
    const int k0beg = blockIdx.z * 1024;

    float acc[4][4];
#pragma unroll
    for (int i = 0; i < 4; ++i)
#pragma unroll
        for (int j = 0; j < 4; ++j) acc[i][j] = 0.f;

#pragma unroll 1
    for (int kc = k0beg; kc < k0beg + 1024; kc += 32) {
#pragma unroll
        for (int it = 0; it < 2; ++it) {
            int idx = tid + it * 256;
            int row = idx >> 3;
            int c4  = (idx & 7) * 4;
            int kap = kc + c4;
            int s = kap >> 8, half = (kap >> 7) & 1, h = kap & 127;
            float4 va = *(const float4*)(o + ((size_t)(m0 + row + 256 * half) * 128 + s) * 128 + h);
            *(float4*)&As[row][c4] = va;
            float4 vw = *(const float4*)(gw + (size_t)(n0 + row) * 32768 + kap);
            *(float4*)&Ws[row][c4] = vw;
        }
        __syncthreads();
#pragma unroll 1
        for (int k0 = 0; k0 < 32; k0 += 4) {
            float4 a4[4], w4[4];
#pragma unroll
            for (int i = 0; i < 4; ++i) a4[i] = *(float4*)&As[ty + 16 * i][k0];
#pragma unroll
            for (int j = 0; j < 4; ++j) w4[j] = *(float4*)&Ws[tx + 16 * j][k0];
#pragma unroll
            for (int i = 0; i < 4; ++i)
#pragma unroll
                for (int j = 0; j < 4; ++j) {
                    acc[i][j] += a4[i].x * w4[j].x + a4[i].y * w4[j].y +
                                 a4[i].z * w4[j].z + a4[i].w * w4[j].w;
                }
        }
        __syncthreads();
    }
#pragma unroll
    for (int i = 0; i < 4; ++i)
#pragma unroll
        for (int j = 0; j < 4; ++j) {
            int r = m0 + ty + 16 * i, c = n0 + tx + 16 * j;
            atomicAdd(&y[r * 128 + c], acc[i][j]);
        }
}

// ---------------- K6: BN + sigmoid-mean + softmax -> weights (128) ----------------
__global__ void gate_reduce(const float* __restrict__ y,
                            const float* __restrict__ gamma,
                            const float* __restrict__ beta,
                            float* __restrict__ wts_ws,
                            float* __restrict__ wts_out)
{
    const int o = threadIdx.x;   // 128 threads
    float sum = 0.f, sumsq = 0.f;
    for (int b = 0; b < 256; ++b) {
        float v = y[b * 128 + o];
        sum += v; sumsq += v * v;
    }
    float m = sum * (1.f / 256.f);
    float var = sumsq * (1.f / 256.f) - m * m;
    float inv = rsqrtf(var + 1e-5f);
    float g = gamma[o], be = beta[o];
    float sw = 0.f;
    for (int b = 0; b < 256; ++b) {
        float v = y[b * 128 + o];
        float t = g * (v - m) * inv + be;
        sw += 1.f / (1.f + __expf(-t));
    }
    float wo = sw * (1.f / 256.f);

    __shared__ float red[128];
    red[o] = wo;
    __syncthreads();
    for (int st = 64; st > 0; st >>= 1) {
        if (o < st) red[o] = fmaxf(red[o], red[o + st]);
        __syncthreads();
    }
    float mx = red[0];
    __syncthreads();
    float e = __expf(wo - mx);
    red[o] = e;
    __syncthreads();
    for (int st = 64; st > 0; st >>= 1) {
        if (o < st) red[o] += red[o + st];
        __syncthreads();
    }
    float r = e / red[0];
    wts_ws[o] = r;
    wts_out[o] = r;
}

// ---------------- K7: fc_out = o2[:, -1, :] @ fc_w^T + fc_b ----------------
__global__ void fc_kern(const float* __restrict__ o2,
                        const float* __restrict__ fw,
                        const float* __restrict__ fb,
                        float* __restrict__ out)
{
    int gid = blockIdx.x * blockDim.x + threadIdx.x;
    if (gid >= 3072) return;
    int b = gid / 6, oo = gid - b * 6;
    const float* xr = o2 + ((size_t)b * 128 + 127) * 128;
    const float* wr = fw + oo * 128;
    float acc = fb[oo];
#pragma unroll 16
    for (int k = 0; k < 128; ++k) acc += xr[k] * wr[k];
    out[gid] = acc;
}

// ---------------- K8: per-pair bandwidth ----------------
__global__ void pair_stats(const float* __restrict__ o1,
                           const float* __restrict__ o2,
                           float* __restrict__ bw)
{
    const int p = blockIdx.x;          // 256 pairs
    const int l = p >> 7, s = p & 127;
    const float* o = l ? o2 : o1;
    const int tid = threadIdx.x;       // 256
    const int h = tid & 127, half = tid >> 7;

    float acc_u = 0.f, acc_sq = 0.f;
    for (int r = 0; r < 256; ++r) {
        int i = half * 256 + r;
        float v = o[((size_t)i * 128 + s) * 128 + h];
        acc_u += v; acc_sq += v * v;
    }
    __shared__ float u2[256];
    __shared__ float red[256];
    u2[tid] = acc_u;
    red[tid] = acc_sq;
    __syncthreads();
    for (int st = 128; st > 0; st >>= 1) {
        if (tid < st) red[tid] += red[tid + st];
        __syncthreads();
    }
    float S1 = red[0];
    __syncthreads();
    float uu = 0.f;
    if (tid < 128) { float t = u2[tid] + u2[tid + 128]; uu = t * t; }
    red[tid] = uu;
    __syncthreads();
    for (int st = 128; st > 0; st >>= 1) {
        if (tid < st) red[tid] += red[tid + st];
        __syncthreads();
    }
    if (tid == 0) {
        float S2 = red[0];
        float d2s = 1024.f * S1 - 2.f * S2;
        bw[p] = d2s / (512.f * 512.f - 512.f) * 0.25f;
    }
}

// ---------------- K9: MMD Gram + 5-kernel sum, symmetric tiles ----------------
__global__ __launch_bounds__(256) void mmd_kern(const float* __restrict__ o1,
                                                const float* __restrict__ o2,
                                                const float* __restrict__ bw,
                                                float* __restrict__ mmdv)
{
    int tp = blockIdx.x;
    int ti, tj;
    if (tp < 4)      { ti = 0; tj = tp; }
    else if (tp < 7) { ti = 1; tj = tp - 3; }
    else if (tp < 9) { ti = 2; tj = tp - 5; }
    else             { ti = 3; tj = 3; }
    const int p = blockIdx.y;
    const int l = p >> 7, s = p & 127;
    const float* o = l ? o2 : o1;
    const float sgn  = ((ti < 2) == (tj < 2)) ? 1.f : -1.f;
    const float coef = sgn * ((ti == tj) ? 1.f : 2.f);

    __shared__ __align__(16) float As[128][36];
    __shared__ __align__(16) float Bs[128][36];
    __shared__ float sqA[128];
    __shared__ float sqB[128];
    __shared__ float rbuf[4];

    const int tid = threadIdx.x;
    const int tx = tid & 15, ty = tid >> 4;

    float acc[8][8];
#pragma unroll
    for (int i = 0; i < 8; ++i)
#pragma unroll
        for (int j = 0; j < 8; ++j) acc[i][j] = 0.f;
    float sqa = 0.f, sqb = 0.f;

#pragma unroll 1
    for (int kc = 0; kc < 128; kc += 32) {
#pragma unroll
        for (int it = 0; it < 4; ++it) {
            int idx = tid + it * 256;           // 0..1023
            int row = idx >> 3;
            int c4  = (idx & 7) * 4;
            float4 va = *(const float4*)(o + ((size_t)(ti * 128 + row) * 128 + s) * 128 + kc + c4);
            *(float4*)&As[row][c4] = va;
            float4 vb = *(const float4*)(o + ((size_t)(tj * 128 + row) * 128 + s) * 128 + kc + c4);
            *(float4*)&Bs[row][c4] = vb;
        }
        __syncthreads();
        if (tid < 128) {
#pragma unroll 1
            for (int k = 0; k < 32; ++k) {
                float va = As[tid][k]; sqa += va * va;
                float vb = Bs[tid][k]; sqb += vb * vb;
            }
        }
#pragma unroll 1
        for (int k0 = 0; k0 < 32; k0 += 4) {
            float4 a4[8], b4[8];
#pragma unroll
            for (int i = 0; i < 8; ++i) a4[i] = *(float4*)&As[ty + 16 * i][k0];
#pragma unroll
            for (int j = 0; j < 8; ++j) b4[j] = *(float4*)&Bs[tx + 16 * j][k0];
#pragma unroll
            for (int i = 0; i < 8; ++i)
#pragma unroll
                for (int j = 0; j < 8; ++j) {
                    acc[i][j] += a4[i].x * b4[j].x + a4[i].y * b4[j].y +
                                 a4[i].z * b4[j].z + a4[i].w * b4[j].w;
                }
        }
        __syncthreads();
    }
    if (tid < 128) { sqA[tid] = sqa; sqB[tid] = sqb; }
    __syncthreads();

    const float bwv = bw[p];
    float c0 = -1.f / bwv;
    float c1 = c0 * 0.5f, c2 = c1 * 0.5f, c3 = c2 * 0.5f, c4v = c3 * 0.5f;
    float tot = 0.f;
#pragma unroll 1
    for (int i = 0; i < 8; ++i) {
        float sa = sqA[ty + 16 * i];
#pragma unroll
        for (int j = 0; j < 8; ++j) {
            float d2 = sa + sqB[tx + 16 * j] - 2.f * acc[i][j];
            float kv = __expf(c0 * d2) + __expf(c1 * d2) + __expf(c2 * d2) +
                       __expf(c3 * d2) + __expf(c4v * d2);
            tot += kv;
        }
    }
    tot *= coef;

    for (int off = 32; off > 0; off >>= 1) tot += __shfl_down(tot, off);
    if ((tid & 63) == 0) rbuf[tid >> 6] = tot;
    __syncthreads();
    if (tid == 0) atomicAdd(&mmdv[p], rbuf[0] + rbuf[1] + rbuf[2] + rbuf[3]);
}

// ---------------- K10: loss = sum(wts * mmd) / 65536 ----------------
__global__ void final_loss(const float* __restrict__ wts,
                           const float* __restrict__ mmdv,
                           float* __restrict__ out)
{
    const int t = threadIdx.x;  // 256
    float v = wts[t] * mmdv[t];
    __shared__ float red[256];
    red[t] = v;
    __syncthreads();
    for (int st = 128; st > 0; st >>= 1) {
        if (t < st) red[t] += red[t + st];
        __syncthreads();
    }
    if (t == 0) out[0] = red[0] * (1.f / 65536.f);
}

// ---------------- launch ----------------
extern "C" void kernel_launch(void* const* d_in, const int* in_sizes, int n_in,
                              void* d_out, int out_size, void* d_ws, size_t ws_size,
                              hipStream_t stream)
{
    (void)in_sizes; (void)n_in; (void)out_size; (void)ws_size;
    const float* x    = (const float*)d_in[0];
    const float* wih0 = (const float*)d_in[1];
    const float* whh0 = (const float*)d_in[2];
    const float* bih0 = (const float*)d_in[3];
    const float* bhh0 = (const float*)d_in[4];
    const float* wih1 = (const float*)d_in[5];
    const float* whh1 = (const float*)d_in[6];
    const float* bih1 = (const float*)d_in[7];
    const float* bhh1 = (const float*)d_in[8];
    const float* gw0  = (const float*)d_in[9];
    const float* bg0  = (const float*)d_in[11];
    const float* bb0  = (const float*)d_in[12];
    const float* gw1  = (const float*)d_in[13];
    const float* bg1  = (const float*)d_in[15];
    const float* bb1  = (const float*)d_in[16];
    const float* fcw  = (const float*)d_in[17];
    const float* fcb  = (const float*)d_in[18];

    float* out = (float*)d_out;
    char*  ws  = (char*)d_ws;
    float* xw   = (float*)(ws + XW_OFF);
    float* o1   = (float*)(ws + O1_OFF);
    float* o2   = (float*)(ws + O2_OFF);
    float* y0   = (float*)(ws + Y0_OFF);
    float* y1   = (float*)(ws + Y1_OFF);
    float* mmdv = (float*)(ws + MMD_OFF);
    float* wts  = (float*)(ws + WTS_OFF);
    float* bwv  = (float*)(ws + BW_OFF);

    hipMemsetAsync(y0, 0, (256 * 128 * 2 + 256) * sizeof(float), stream);

    gemm64<<<dim3(1024, 6), 256, 0, stream>>>(x, wih0, bih0, xw, 65536, 384, 128);
    gru_scan<<<512, 384, 0, stream>>>(xw, whh0, bhh0, o1);
    gemm64<<<dim3(1024, 6), 256, 0, stream>>>(o1, wih1, bih1, xw, 65536, 384, 128);
    gru_scan<<<512, 384, 0, stream>>>(xw, whh1, bhh1, o2);

    gate_gemm<<<dim3(4, 2, 32), 256, 0, stream>>>(o1, gw0, y0);
    gate_gemm<<<dim3(4, 2, 32), 256, 0, stream>>>(o2, gw1, y1);
    gate_reduce<<<1, 128, 0, stream>>>(y0, bg0, bb0, wts, out + 3073);
    gate_reduce<<<1, 128, 0, stream>>>(y1, bg1, bb1, wts + 128, out + 3073 + 128);

    fc_kern<<<12, 256, 0, stream>>>(o2, fcw, fcb, out);

    pair_stats<<<256, 256, 0, stream>>>(o1, o2, bwv);
    mmd_kern<<<dim3(10, 256), 256, 0, stream>>>(o1, o2, bwv, mmdv);
    final_loss<<<1, 256, 0, stream>>>(wts, mmdv, out + 3072);
}

// Round 3
// 1275.408 us; speedup vs baseline: 1.6017x; 1.0012x over previous
//
#include <hip/hip_runtime.h>
#include <math.h>

// ---------------- workspace layout (bytes) ----------------
constexpr size_t XW_OFF  = 0;                                   // 65536*384 f32 = 96 MB (dead after 2nd gru -> reused for norms)
constexpr size_t O1_OFF  = XW_OFF + 65536ull * 384 * 4;         // 32 MB
constexpr size_t O2_OFF  = O1_OFF + 512ull * 128 * 128 * 4;     // 32 MB
constexpr size_t Y0_OFF  = O2_OFF + 512ull * 128 * 128 * 4;     // 128 KB
constexpr size_t Y1_OFF  = Y0_OFF + 256ull * 128 * 4;           // 128 KB
constexpr size_t MMD_OFF = Y1_OFF + 256ull * 128 * 4;           // 1 KB
constexpr size_t WTS_OFF = MMD_OFF + 256 * 4;                   // 1 KB
constexpr size_t BW_OFF  = WTS_OFF + 256 * 4;                   // 1 KB
constexpr size_t NRM_OFF = XW_OFF;                              // norms[2][128][512] f32 = 512 KB (aliases xw)

// ---------------- K1/K3: C[M][N] = A[M][K] @ W[N][K]^T + bias[N] ----------------
__global__ __launch_bounds__(256) void gemm64(const float* __restrict__ A,
                                              const float* __restrict__ W,
                                              const float* __restrict__ bias,
                                              float* __restrict__ C,
                                              int M, int N, int K)
{
    __shared__ __align__(16) float As[64][36];
    __shared__ __align__(16) float Ws[64][36];
    const int tid = threadIdx.x;
    const int tx = tid & 15, ty = tid >> 4;
    const int m0 = blockIdx.x * 64, n0 = blockIdx.y * 64;

    float acc[4][4];
#pragma unroll
    for (int i = 0; i < 4; ++i)
#pragma unroll
        for (int j = 0; j < 4; ++j) acc[i][j] = 0.f;

#pragma unroll 1
    for (int kc = 0; kc < K; kc += 32) {
#pragma unroll
        for (int it = 0; it < 2; ++it) {
            int idx = tid + it * 256;          // 0..511
            int row = idx >> 3;
            int c4  = (idx & 7) * 4;
            float4 va = *(const float4*)(A + (size_t)(m0 + row) * K + kc + c4);
            *(float4*)&As[row][c4] = va;
            float4 vw = *(const float4*)(W + (size_t)(n0 + row) * K + kc + c4);
            *(float4*)&Ws[row][c4] = vw;
        }
        __syncthreads();
#pragma unroll 1
        for (int k0 = 0; k0 < 32; k0 += 4) {
            float4 a4[4], w4[4];
#pragma unroll
            for (int i = 0; i < 4; ++i) a4[i] = *(float4*)&As[ty + 16 * i][k0];
#pragma unroll
            for (int j = 0; j < 4; ++j) w4[j] = *(float4*)&Ws[tx + 16 * j][k0];
#pragma unroll
            for (int i = 0; i < 4; ++i)
#pragma unroll
                for (int j = 0; j < 4; ++j) {
                    acc[i][j] += a4[i].x * w4[j].x + a4[i].y * w4[j].y +
                                 a4[i].z * w4[j].z + a4[i].w * w4[j].w;
                }
        }
        __syncthreads();
    }
#pragma unroll
    for (int i = 0; i < 4; ++i)
#pragma unroll
        for (int j = 0; j < 4; ++j) {
            int r = m0 + ty + 16 * i, c = n0 + tx + 16 * j;
            C[(size_t)r * N + c] = acc[i][j] + bias[c];
        }
}

// ---------------- K2/K4: GRU scan, one block per batch row ----------------
__global__ __launch_bounds__(384, 3) void gru_scan(const float* __restrict__ xw,
                                                   const float* __restrict__ whh,
                                                   const float* __restrict__ bhh,
                                                   float* __restrict__ out)
{
    const int b = blockIdx.x;
    const int j = threadIdx.x;
    float w[128];
    const float* wr = whh + (size_t)j * 128;
#pragma unroll
    for (int k = 0; k < 128; k += 4) {
        float4 t = *(const float4*)(wr + k);
        w[k] = t.x; w[k + 1] = t.y; w[k + 2] = t.z; w[k + 3] = t.w;
    }
    const float bj = bhh[j];
    __shared__ __align__(16) float h_s[128];
    __shared__ float rz_s[256];
    __shared__ float xn_s[128];
    __shared__ float hn_s[128];
    if (j < 128) h_s[j] = 0.f;
    __syncthreads();

    const float* xwb = xw + (size_t)b * 128 * 384;
    const int g = j >> 7, u = j & 127;

#pragma unroll 1
    for (int t = 0; t < 128; ++t) {
        float xv = xwb[t * 384 + j];
        float acc = bj;
#pragma unroll
        for (int k = 0; k < 128; k += 4) {
            float4 hv = *(float4*)&h_s[k];
            acc += w[k] * hv.x + w[k + 1] * hv.y + w[k + 2] * hv.z + w[k + 3] * hv.w;
        }
        if (g == 0)      rz_s[u] = xv + acc;
        else if (g == 1) rz_s[128 + u] = xv + acc;
        else             { xn_s[u] = xv; hn_s[u] = acc; }
        __syncthreads();
        if (j < 128) {
            float r = 1.f / (1.f + __expf(-rz_s[j]));
            float z = 1.f / (1.f + __expf(-rz_s[128 + j]));
            float xa = xn_s[j] + r * hn_s[j];
            float e = __expf(-2.f * fabsf(xa));
            float th = (1.f - e) / (1.f + e);
            th = copysignf(th, xa);
            float hnew = (1.f - z) * th + z * h_s[j];
            h_s[j] = hnew;
            out[((size_t)b * 128 + t) * 128 + j] = hnew;
        }
        __syncthreads();
    }
}

// ---------------- K5: y[256][128] += xall @ gw^T (split-K, atomic) ----------------
__global__ __launch_bounds__(256) void gate_gemm(const float* __restrict__ o,
                                                 const float* __restrict__ gw,
                                                 float* __restrict__ y)
{
    __shared__ __align__(16) float As[64][36];
    __shared__ __align__(16) float Ws[64][36];
    const int tid = threadIdx.x;
    const int tx = tid & 15, ty = tid >> 4;
    const int m0 = blockIdx.x * 64, n0 = blockIdx.y * 64;
    const int k0beg = blockIdx.z * 1024;

    float acc[4][4];
#pragma unroll
    for (int i = 0; i < 4; ++i)
#pragma unroll
        for (int j = 0; j < 4; ++j) acc[i][j] = 0.f;

#pragma unroll 1
    for (int kc = k0beg; kc < k0beg + 1024; kc += 32) {
#pragma unroll
        for (int it = 0; it < 2; ++it) {
            int idx = tid + it * 256;
            int row = idx >> 3;
            int c4  = (idx & 7) * 4;
            int kap = kc + c4;
            int s = kap >> 8, half = (kap >> 7) & 1, h = kap & 127;
            float4 va = *(const float4*)(o + ((size_t)(m0 + row + 256 * half) * 128 + s) * 128 + h);
            *(float4*)&As[row][c4] = va;
            float4 vw = *(const float4*)(gw + (size_t)(n0 + row) * 32768 + kap);
            *(float4*)&Ws[row][c4] = vw;
        }
        __syncthreads();
#pragma unroll 1
        for (int k0 = 0; k0 < 32; k0 += 4) {
            float4 a4[4], w4[4];
#pragma unroll
            for (int i = 0; i < 4; ++i) a4[i] = *(float4*)&As[ty + 16 * i][k0];
#pragma unroll
            for (int j = 0; j < 4; ++j) w4[j] = *(float4*)&Ws[tx + 16 * j][k0];
#pragma unroll
            for (int i = 0; i < 4; ++i)
#pragma unroll
                for (int j = 0; j < 4; ++j) {
                    acc[i][j] += a4[i].x * w4[j].x + a4[i].y * w4[j].y +
                                 a4[i].z * w4[j].z + a4[i].w * w4[j].w;
                }
        }
        __syncthreads();
    }
#pragma unroll
    for (int i = 0; i < 4; ++i)
#pragma unroll
        for (int j = 0; j < 4; ++j) {
            int r = m0 + ty + 16 * i, c = n0 + tx + 16 * j;
            atomicAdd(&y[r * 128 + c], acc[i][j]);
        }
}

// ---------------- K6: BN + sigmoid-mean + softmax -> weights (128) ----------------
__global__ void gate_reduce(const float* __restrict__ y,
                            const float* __restrict__ gamma,
                            const float* __restrict__ beta,
                            float* __restrict__ wts_ws,
                            float* __restrict__ wts_out)
{
    const int o = threadIdx.x;   // 128 threads
    float sum = 0.f, sumsq = 0.f;
    for (int b = 0; b < 256; ++b) {
        float v = y[b * 128 + o];
        sum += v; sumsq += v * v;
    }
    float m = sum * (1.f / 256.f);
    float var = sumsq * (1.f / 256.f) - m * m;
    float inv = rsqrtf(var + 1e-5f);
    float g = gamma[o], be = beta[o];
    float sw = 0.f;
    for (int b = 0; b < 256; ++b) {
        float v = y[b * 128 + o];
        float t = g * (v - m) * inv + be;
        sw += 1.f / (1.f + __expf(-t));
    }
    float wo = sw * (1.f / 256.f);

    __shared__ float red[128];
    red[o] = wo;
    __syncthreads();
    for (int st = 64; st > 0; st >>= 1) {
        if (o < st) red[o] = fmaxf(red[o], red[o + st]);
        __syncthreads();
    }
    float mx = red[0];
    __syncthreads();
    float e = __expf(wo - mx);
    red[o] = e;
    __syncthreads();
    for (int st = 64; st > 0; st >>= 1) {
        if (o < st) red[o] += red[o + st];
        __syncthreads();
    }
    float r = e / red[0];
    wts_ws[o] = r;
    wts_out[o] = r;
}

// ---------------- K7: fc_out = o2[:, -1, :] @ fc_w^T + fc_b ----------------
__global__ void fc_kern(const float* __restrict__ o2,
                        const float* __restrict__ fw,
                        const float* __restrict__ fb,
                        float* __restrict__ out)
{
    int gid = blockIdx.x * blockDim.x + threadIdx.x;
    if (gid >= 3072) return;
    int b = gid / 6, oo = gid - b * 6;
    const float* xr = o2 + ((size_t)b * 128 + 127) * 128;
    const float* wr = fw + oo * 128;
    float acc = fb[oo];
#pragma unroll 16
    for (int k = 0; k < 128; ++k) acc += xr[k] * wr[k];
    out[gid] = acc;
}

// ---------------- K8a: per-row norms: norms[l][s][i] = sum_h o_l[i][s][h]^2 ----------------
__global__ __launch_bounds__(512) void row_norms(const float* __restrict__ o1,
                                                 const float* __restrict__ o2,
                                                 float* __restrict__ norms)
{
    const int s = blockIdx.x;          // 128
    const int l = blockIdx.y;          // 2
    const float* o = l ? o2 : o1;
    const int i = threadIdx.x;         // 512 rows
    const float* r = o + ((size_t)i * 128 + s) * 128;
    float acc = 0.f;
#pragma unroll
    for (int k = 0; k < 128; k += 4) {
        float4 v = *(const float4*)(r + k);
        acc += v.x * v.x + v.y * v.y + v.z * v.z + v.w * v.w;
    }
    norms[((size_t)l * 128 + s) * 512 + i] = acc;
}

// ---------------- K8b: per-pair bandwidth ----------------
__global__ void pair_stats(const float* __restrict__ o1,
                           const float* __restrict__ o2,
                           float* __restrict__ bw)
{
    const int p = blockIdx.x;          // 256 pairs
    const int l = p >> 7, s = p & 127;
    const float* o = l ? o2 : o1;
    const int tid = threadIdx.x;       // 256
    const int h = tid & 127, half = tid >> 7;

    float acc_u = 0.f, acc_sq = 0.f;
    for (int r = 0; r < 256; ++r) {
        int i = half * 256 + r;
        float v = o[((size_t)i * 128 + s) * 128 + h];
        acc_u += v; acc_sq += v * v;
    }
    __shared__ float u2[256];
    __shared__ float red[256];
    u2[tid] = acc_u;
    red[tid] = acc_sq;
    __syncthreads();
    for (int st = 128; st > 0; st >>= 1) {
        if (tid < st) red[tid] += red[tid + st];
        __syncthreads();
    }
    float S1 = red[0];
    __syncthreads();
    float uu = 0.f;
    if (tid < 128) { float t = u2[tid] + u2[tid + 128]; uu = t * t; }
    red[tid] = uu;
    __syncthreads();
    for (int st = 128; st > 0; st >>= 1) {
        if (tid < st) red[tid] += red[tid + st];
        __syncthreads();
    }
    if (tid == 0) {
        float S2 = red[0];
        float d2s = 1024.f * S1 - 2.f * S2;
        bw[p] = d2s / (512.f * 512.f - 512.f) * 0.25f;
    }
}

// ---------------- K9: MMD Gram + 5-kernel sum, symmetric tiles ----------------
// 1-D grid of 2560, xcd-major decode so a pair's 10 tile-blocks share an XCD's L2.
__global__ __launch_bounds__(256) void mmd_kern(const float* __restrict__ o1,
                                                const float* __restrict__ o2,
                                                const float* __restrict__ norms,
                                                const float* __restrict__ bw,
                                                float* __restrict__ mmdv)
{
    // xcd-major virtual index: lin = r*320 + q, r = lin%8 is the XCD slot
    const int lin = blockIdx.x;               // 0..2559
    const int v   = (lin & 7) * 320 + (lin >> 3);
    const int p   = v / 10;                   // pair
    const int tp  = v - p * 10;               // tile-pair
    int ti, tj;
    if (tp < 4)      { ti = 0; tj = tp; }
    else if (tp < 7) { ti = 1; tj = tp - 3; }
    else if (tp < 9) { ti = 2; tj = tp - 5; }
    else             { ti = 3; tj = 3; }
    const int l = p >> 7, s = p & 127;
    const float* o = l ? o2 : o1;
    const float sgn  = ((ti < 2) == (tj < 2)) ? 1.f : -1.f;
    const float coef = sgn * ((ti == tj) ? 1.f : 2.f);

    __shared__ __align__(16) float As[128][36];
    __shared__ __align__(16) float Bs[128][36];
    __shared__ float rbuf[4];

    const int tid = threadIdx.x;
    const int tx = tid & 15, ty = tid >> 4;

    float acc[8][8];
#pragma unroll
    for (int i = 0; i < 8; ++i)
#pragma unroll
        for (int j = 0; j < 8; ++j) acc[i][j] = 0.f;

#pragma unroll 1
    for (int kc = 0; kc < 128; kc += 32) {
#pragma unroll
        for (int it = 0; it < 4; ++it) {
            int idx = tid + it * 256;           // 0..1023
            int row = idx >> 3;
            int c4  = (idx & 7) * 4;
            float4 va = *(const float4*)(o + ((size_t)(ti * 128 + row) * 128 + s) * 128 + kc + c4);
            *(float4*)&As[row][c4] = va;
            float4 vb = *(const float4*)(o + ((size_t)(tj * 128 + row) * 128 + s) * 128 + kc + c4);
            *(float4*)&Bs[row][c4] = vb;
        }
        __syncthreads();
#pragma unroll 1
        for (int k0 = 0; k0 < 32; k0 += 4) {
            float4 b4[8];
#pragma unroll
            for (int j = 0; j < 8; ++j) b4[j] = *(float4*)&Bs[tx + 16 * j][k0];
#pragma unroll
            for (int i = 0; i < 8; ++i) {
                float4 a4 = *(float4*)&As[ty + 16 * i][k0];
#pragma unroll
                for (int j = 0; j < 8; ++j) {
                    acc[i][j] += a4.x * b4[j].x + a4.y * b4[j].y +
                                 a4.z * b4[j].z + a4.w * b4[j].w;
                }
            }
        }
        __syncthreads();
    }

    const float* np_ = norms + (size_t)p * 512;
    float na[8], nb[8];
#pragma unroll
    for (int i = 0; i < 8; ++i) na[i] = np_[ti * 128 + ty + 16 * i];
#pragma unroll
    for (int j = 0; j < 8; ++j) nb[j] = np_[tj * 128 + tx + 16 * j];

    const float bwv = bw[p];
    float c0 = -1.f / bwv;
    float c1 = c0 * 0.5f, c2 = c1 * 0.5f, c3 = c2 * 0.5f, c4v = c3 * 0.5f;
    float tot = 0.f;
#pragma unroll 1
    for (int i = 0; i < 8; ++i) {
#pragma unroll
        for (int j = 0; j < 8; ++j) {
            float d2 = na[i] + nb[j] - 2.f * acc[i][j];
            float kv = __expf(c0 * d2) + __expf(c1 * d2) + __expf(c2 * d2) +
                       __expf(c3 * d2) + __expf(c4v * d2);
            tot += kv;
        }
    }
    tot *= coef;

    for (int off = 32; off > 0; off >>= 1) tot += __shfl_down(tot, off);
    if ((tid & 63) == 0) rbuf[tid >> 6] = tot;
    __syncthreads();
    if (tid == 0) atomicAdd(&mmdv[p], rbuf[0] + rbuf[1] + rbuf[2] + rbuf[3]);
}

// ---------------- K10: loss = sum(wts * mmd) / 65536 ----------------
__global__ void final_loss(const float* __restrict__ wts,
                           const float* __restrict__ mmdv,
                           float* __restrict__ out)
{
    const int t = threadIdx.x;  // 256
    float v = wts[t] * mmdv[t];
    __shared__ float red[256];
    red[t] = v;
    __syncthreads();
    for (int st = 128; st > 0; st >>= 1) {
        if (t < st) red[t] += red[t + st];
        __syncthreads();
    }
    if (t == 0) out[0] = red[0] * (1.f / 65536.f);
}

// ---------------- launch ----------------
extern "C" void kernel_launch(void* const* d_in, const int* in_sizes, int n_in,
                              void* d_out, int out_size, void* d_ws, size_t ws_size,
                              hipStream_t stream)
{
    (void)in_sizes; (void)n_in; (void)out_size; (void)ws_size;
    const float* x    = (const float*)d_in[0];
    const float* wih0 = (const float*)d_in[1];
    const float* whh0 = (const float*)d_in[2];
    const float* bih0 = (const float*)d_in[3];
    const float* bhh0 = (const float*)d_in[4];
    const float* wih1 = (const float*)d_in[5];
    const float* whh1 = (const float*)d_in[6];
    const float* bih1 = (const float*)d_in[7];
    const float* bhh1 = (const float*)d_in[8];
    const float* gw0  = (const float*)d_in[9];
    const float* bg0  = (const float*)d_in[11];
    const float* bb0  = (const float*)d_in[12];
    const float* gw1  = (const float*)d_in[13];
    const float* bg1  = (const float*)d_in[15];
    const float* bb1  = (const float*)d_in[16];
    const float* fcw  = (const float*)d_in[17];
    const float* fcb  = (const float*)d_in[18];

    float* out = (float*)d_out;
    char*  ws  = (char*)d_ws;
    float* xw   = (float*)(ws + XW_OFF);
    float* o1   = (float*)(ws + O1_OFF);
    float* o2   = (float*)(ws + O2_OFF);
    float* y0   = (float*)(ws + Y0_OFF);
    float* y1   = (float*)(ws + Y1_OFF);
    float* mmdv = (float*)(ws + MMD_OFF);
    float* wts  = (float*)(ws + WTS_OFF);
    float* bwv  = (float*)(ws + BW_OFF);
    float* nrm  = (float*)(ws + NRM_OFF);   // aliases xw; valid after 2nd gru_scan

    hipMemsetAsync(y0, 0, (256 * 128 * 2 + 256) * sizeof(float), stream);

    gemm64<<<dim3(1024, 6), 256, 0, stream>>>(x, wih0, bih0, xw, 65536, 384, 128);
    gru_scan<<<512, 384, 0, stream>>>(xw, whh0, bhh0, o1);
    gemm64<<<dim3(1024, 6), 256, 0, stream>>>(o1, wih1, bih1, xw, 65536, 384, 128);
    gru_scan<<<512, 384, 0, stream>>>(xw, whh1, bhh1, o2);

    gate_gemm<<<dim3(4, 2, 32), 256, 0, stream>>>(o1, gw0, y0);
    gate_gemm<<<dim3(4, 2, 32), 256, 0, stream>>>(o2, gw1, y1);
    gate_reduce<<<1, 128, 0, stream>>>(y0, bg0, bb0, wts, out + 3073);
    gate_reduce<<<1, 128, 0, stream>>>(y1, bg1, bb1, wts + 128, out + 3073 + 128);

    fc_kern<<<12, 256, 0, stream>>>(o2, fcw, fcb, out);

    row_norms<<<dim3(128, 2), 512, 0, stream>>>(o1, o2, nrm);   // xw dead from here
    pair_stats<<<256, 256, 0, stream>>>(o1, o2, bwv);
    mmd_kern<<<2560, 256, 0, stream>>>(o1, o2, nrm, bwv, mmdv);
    final_loss<<<1, 256, 0, stream>>>(wts, mmdv, out + 3072);
}